// Round 5
// baseline (358.816 us; speedup 1.0000x reference)
//
#include <hip/hip_runtime.h>
#include <math.h>

#define NUM_MOE 64
#define DIM 64
#define CH 16          // float4 chunks per x row
#define ETILE 16

// Pin a float4 into registers as an asm-defined value: the compiler cannot
// rematerialize the originating global load (R3's failure mode).
#define PIN4(v) asm volatile("" : "+v"(v.x), "+v"(v.y), "+v"(v.z), "+v"(v.w))

// 64-thread blocks: empirically (R4) the allocator grants 128 VGPRs at this
// block size (256-thread blocks clamped to 48-64 and spilled, R2/R3).
// lane = token, x row held in 16 float4 = 64 VGPRs, experts in 4 groups of
// 16 accumulators -> peak live ~95 VGPR < 128. No LDS -> occupancy is
// VGPR-limited at 4 waves/SIMD (16/CU), 2.5x R4's LDS-limited 20%.
__global__ __launch_bounds__(64, 4)
void moe_router_kernel(const float* __restrict__ x,
                       const float* __restrict__ W,
                       float* __restrict__ out,
                       int ntok) {
    const int lane = threadIdx.x;                    // 0..63
    const int t    = blockIdx.x * 64 + lane;         // one token per lane
    if (t >= ntok) return;

    const float4* __restrict__ W4 = reinterpret_cast<const float4*>(W);

    // ---- x row -> 16 float4 registers, pinned ----
    const float4* __restrict__ xr4 = reinterpret_cast<const float4*>(x) + (size_t)t * CH;
    float4 xv[CH];
    #pragma unroll
    for (int k = 0; k < CH; ++k) xv[k] = xr4[k];
    #pragma unroll
    for (int k = 0; k < CH; ++k) PIN4(xv[k]);

    float m1 = -INFINITY, m2 = -INFINITY, Z = 0.0f;
    int   i1 = 0, i2 = 0;

    #pragma unroll 1                                 // groups rolled: bounds live regs
    for (int g = 0; g < NUM_MOE / ETILE; ++g) {
        float acc[ETILE];
        #pragma unroll
        for (int e = 0; e < ETILE; ++e) acc[e] = 0.0f;

        #pragma unroll
        for (int k = 0; k < CH; ++k) {
            const float4 xk = xv[k];
            #pragma unroll
            for (int e = 0; e < ETILE; ++e) {
                // provably-uniform address, compile-time offset <16KB:
                // s_load_dwordx4 W, imm -> scalar operand slot of v_fmac
                const float4 wv = W4[(g * ETILE + e) * CH + k];
                float a = acc[e];
                a = fmaf(xk.x, wv.x, a);
                a = fmaf(xk.y, wv.y, a);
                a = fmaf(xk.z, wv.z, a);
                a = fmaf(xk.w, wv.w, a);
                acc[e] = a;
            }
        }

        // fold group into running Z + exact top-2 (strict '>': lowest index
        // wins ties, matching lax.top_k; earlier groups win correctly)
        #pragma unroll
        for (int e = 0; e < ETILE; ++e) {
            const float v  = acc[e];
            const int   ge = g * ETILE + e;
            Z += __expf(v);                          // logits ~N(0,1): no max-sub
            const bool b1 = v > m1;
            const bool b2 = v > m2;
            i2 = b1 ? i1 : (b2 ? ge : i2);
            m2 = b1 ? m1 : (b2 ? v : m2);
            i1 = b1 ? ge : i1;
            m1 = b1 ? v  : m1;
        }
    }

    // second softmax over the two kept probs:
    // out[i1] = sigmoid((exp(m1)-exp(m2))/Z), out[i2] = 1 - out[i1]
    const float E1  = __expf(m1), E2 = __expf(m2);
    const float d12 = (E1 - E2) / Z;
    const float w1  = 1.0f / (1.0f + __expf(-d12));
    const float w2  = 1.0f - w1;

    // Build sparse row in registers (compile-time j vs runtime i1/i2 ->
    // v_cmp + cndmask). Each lane writes its whole row: every 64B line is
    // fully written by one lane -> L2 write-combines to exactly 64 MiB.
    float4* __restrict__ o4 = reinterpret_cast<float4*>(out) + (size_t)t * CH;
    #pragma unroll
    for (int k = 0; k < CH; ++k) {
        const int j = 4 * k;
        float4 v;
        v.x = (j + 0 == i1) ? w1 : ((j + 0 == i2) ? w2 : 0.0f);
        v.y = (j + 1 == i1) ? w1 : ((j + 1 == i2) ? w2 : 0.0f);
        v.z = (j + 2 == i1) ? w1 : ((j + 2 == i2) ? w2 : 0.0f);
        v.w = (j + 3 == i1) ? w1 : ((j + 3 == i2) ? w2 : 0.0f);
        o4[k] = v;
    }
}

extern "C" void kernel_launch(void* const* d_in, const int* in_sizes, int n_in,
                              void* d_out, int out_size, void* d_ws, size_t ws_size,
                              hipStream_t stream) {
    const float* x = (const float*)d_in[0];
    const float* W = (const float*)d_in[1];
    float* out = (float*)d_out;
    int ntok = in_sizes[0] / DIM;                    // 262144

    int blocks = (ntok + 63) / 64;                   // 4096 one-wave blocks
    moe_router_kernel<<<blocks, 64, 0, stream>>>(x, W, out, ntok);
}

// Round 6
// 252.742 us; speedup vs baseline: 1.4197x; 1.4197x over previous
//
#include <hip/hip_runtime.h>
#include <math.h>

#define NUM_MOE 64
#define DIM 64

// intra-quad lane permutes via DPP quad_perm: VALU-pipe (~2cy), no LDS pipe.
// ctrl = sel0 | sel1<<2 | sel2<<4 | sel3<<6
#define QP_XOR1 0xB1   // (1,0,3,2)
#define QP_XOR2 0x4E   // (2,3,0,1)
template <int CTRL>
__device__ __forceinline__ float qperm_f(float v) {
    return __int_as_float(__builtin_amdgcn_mov_dpp(__float_as_int(v), CTRL, 0xF, 0xF, true));
}
template <int CTRL>
__device__ __forceinline__ int qperm_i(int v) {
    return __builtin_amdgcn_mov_dpp(v, CTRL, 0xF, 0xF, true);
}

// 4 lanes per token, split by DIMENSION. Designed for the 64-VGPR budget the
// allocator insists on (R1-R5): peak live ~55 regs, nothing big enough to
// spill or rematerialize. All cross-lane ops are intra-quad DPP.
__global__ __launch_bounds__(64)
void moe_router_kernel(const float* __restrict__ x,
                       const float* __restrict__ W,
                       float* __restrict__ out,
                       int ntok) {
    const int lane = threadIdx.x;        // 0..63
    const int tq   = lane >> 2;          // token-in-batch 0..15
    const int q    = lane & 3;           // dim quarter 0..3
    const int t    = blockIdx.x * 16 + tq;
    if (t >= ntok) return;               // whole quads exit together (safe for DPP)

    // this lane's x quarter: dims [16q, 16q+16) -> 16 VGPRs
    const float4* __restrict__ x4 = reinterpret_cast<const float4*>(x) + (size_t)t * 16 + q * 4;
    const float4 xa = x4[0], xb = x4[1], xc = x4[2], xd = x4[3];

    // W chunk base for this lane's dim quarter: W4[e*16 + kk] = W[e][16q+4kk ..]
    const float4* __restrict__ W4 = reinterpret_cast<const float4*>(W) + q * 4;

    const bool qb0 = (q & 1) != 0;
    const bool qb1 = (q & 2) != 0;

    float m1 = -INFINITY, m2 = -INFINITY, Zp = 0.0f;  // Zp: per-lane partial
    int   i1 = 0, i2 = 0;

    #pragma unroll 2
    for (int c = 0; c < NUM_MOE / 8; ++c) {
        // partial dots (this lane's 16 dims) for experts [8c, 8c+8)
        float acc[8];
        #pragma unroll
        for (int i = 0; i < 8; ++i) {
            const int e = c * 8 + i;
            const float4 w0 = W4[e * 16 + 0];
            const float4 w1v = W4[e * 16 + 1];
            const float4 w2v = W4[e * 16 + 2];
            const float4 w3v = W4[e * 16 + 3];
            float a = xa.x * w0.x;
            a = fmaf(xa.y, w0.y, a);  a = fmaf(xa.z, w0.z, a);  a = fmaf(xa.w, w0.w, a);
            a = fmaf(xb.x, w1v.x, a); a = fmaf(xb.y, w1v.y, a);
            a = fmaf(xb.z, w1v.z, a); a = fmaf(xb.w, w1v.w, a);
            a = fmaf(xc.x, w2v.x, a); a = fmaf(xc.y, w2v.y, a);
            a = fmaf(xc.z, w2v.z, a); a = fmaf(xc.w, w2v.w, a);
            a = fmaf(xd.x, w3v.x, a); a = fmaf(xd.y, w3v.y, a);
            a = fmaf(xd.z, w3v.z, a); a = fmaf(xd.w, w3v.w, a);
            acc[i] = a;
        }
        // quad butterfly: full 64-dim dot in every lane (2 DPP adds per value)
        #pragma unroll
        for (int i = 0; i < 8; ++i) {
            float v = acc[i];
            v += qperm_f<QP_XOR1>(v);
            v += qperm_f<QP_XOR2>(v);
            acc[i] = v;
        }
        // split fold: lane q folds experts {8c+2q, 8c+2q+1} (static ternaries,
        // no runtime array index -> no scratch). Strict '>' + ascending order
        // per lane preserves lowest-index-wins ties.
        #pragma unroll
        for (int s = 0; s < 2; ++s) {
            const float v = qb1 ? (qb0 ? acc[6 + s] : acc[4 + s])
                                : (qb0 ? acc[2 + s] : acc[0 + s]);
            const int  ge = c * 8 + 2 * q + s;
            Zp += __expf(v);                    // logits ~N(0,1): no max-sub
            const bool b1 = v > m1;
            const bool b2 = v > m2;
            i2 = b1 ? i1 : (b2 ? ge : i2);
            m2 = b1 ? m1 : (b2 ? v : m2);
            i1 = b1 ? ge : i1;
            m1 = b1 ? v  : m1;
        }
    }

    // merge the 4 disjoint top-2 sets + partial Z across the quad.
    // Explicit (value, index) tie-break => exact lax.top_k semantics.
    {
        // step 1: XOR1 partner
        float m1o = qperm_f<QP_XOR1>(m1), m2o = qperm_f<QP_XOR1>(m2), Zo = qperm_f<QP_XOR1>(Zp);
        int   i1o = qperm_i<QP_XOR1>(i1), i2o = qperm_i<QP_XOR1>(i2);
        Zp += Zo;
        bool bw = (m1o > m1) || (m1o == m1 && i1o < i1);
        float Wm1 = bw ? m1o : m1;  int Wi1 = bw ? i1o : i1;
        float Wm2 = bw ? m2o : m2;  int Wi2 = bw ? i2o : i2;
        float Lm1 = bw ? m1 : m1o;  int Li1 = bw ? i1 : i1o;
        bool b2 = (Wm2 > Lm1) || (Wm2 == Lm1 && Wi2 < Li1);
        m1 = Wm1; i1 = Wi1;
        m2 = b2 ? Wm2 : Lm1; i2 = b2 ? Wi2 : Li1;

        // step 2: XOR2 partner
        m1o = qperm_f<QP_XOR2>(m1); m2o = qperm_f<QP_XOR2>(m2); Zo = qperm_f<QP_XOR2>(Zp);
        i1o = qperm_i<QP_XOR2>(i1); i2o = qperm_i<QP_XOR2>(i2);
        Zp += Zo;
        bw = (m1o > m1) || (m1o == m1 && i1o < i1);
        Wm1 = bw ? m1o : m1;  Wi1 = bw ? i1o : i1;
        Wm2 = bw ? m2o : m2;  Wi2 = bw ? i2o : i2;
        Lm1 = bw ? m1 : m1o;  Li1 = bw ? i1 : i1o;
        b2 = (Wm2 > Lm1) || (Wm2 == Lm1 && Wi2 < Li1);
        m1 = Wm1; i1 = Wi1;
        m2 = b2 ? Wm2 : Lm1; i2 = b2 ? Wi2 : Li1;
    }

    // out[i1] = sigmoid((exp(m1)-exp(m2))/Z), out[i2] = 1 - out[i1]
    const float E1  = __expf(m1), E2 = __expf(m2);
    const float d12 = (E1 - E2) / Zp;
    const float w1  = 1.0f / (1.0f + __expf(-d12));
    const float w2  = 1.0f - w1;

    // lane q writes experts [16q, 16q+16): addr = lane*64B + kk*16B -> each
    // lane fully owns one 64B line => clean write-combining to exactly 64MB.
    float4* __restrict__ o4 = reinterpret_cast<float4*>(out) + (size_t)t * 16 + q * 4;
    #pragma unroll
    for (int kk = 0; kk < 4; ++kk) {
        const int j = q * 16 + kk * 4;
        float4 v;
        v.x = (j + 0 == i1) ? w1 : ((j + 0 == i2) ? w2 : 0.0f);
        v.y = (j + 1 == i1) ? w1 : ((j + 1 == i2) ? w2 : 0.0f);
        v.z = (j + 2 == i1) ? w1 : ((j + 2 == i2) ? w2 : 0.0f);
        v.w = (j + 3 == i1) ? w1 : ((j + 3 == i2) ? w2 : 0.0f);
        o4[kk] = v;
    }
}

extern "C" void kernel_launch(void* const* d_in, const int* in_sizes, int n_in,
                              void* d_out, int out_size, void* d_ws, size_t ws_size,
                              hipStream_t stream) {
    const float* x = (const float*)d_in[0];
    const float* W = (const float*)d_in[1];
    float* out = (float*)d_out;
    int ntok = in_sizes[0] / DIM;                 // 262144

    int blocks = (ntok + 15) / 16;                // 16 tokens per 64-thread block
    moe_router_kernel<<<blocks, 64, 0, stream>>>(x, W, out, ntok);
}

// Round 7
// 63.394 us; speedup vs baseline: 5.6601x; 3.9869x over previous
//
#include <hip/hip_runtime.h>
#include <math.h>

#define NUM_MOE 64
#define DIM 64
#define CH 16            // float4 chunks per row
#define TOK 64           // tokens per block
#define NW 4             // waves per block
#define ET 8             // experts per inner pass (2 passes per wave)

// 4-wave cooperative block. x tile (64 tokens) staged once in XOR-swizzled
// LDS, shared by 4 waves; wave w computes its 16-expert slice for all 64
// tokens (lane = token -> epilogue folds are per-lane, ~free). W goes
// through the SCALAR path (uniform base via readfirstlane + compile-time
// offsets) so the inner loop has zero VMEM. Per-lane live state ~35 VGPR:
// fits the 48-reg clamp the allocator imposes on 256-thread blocks (R2/R3).
__global__ __launch_bounds__(256)
void moe_router_kernel(const float* __restrict__ x,
                       const float* __restrict__ W,
                       float* __restrict__ out,
                       int ntok) {
    __shared__ float4 xs[CH * TOK];                  // [chunk][token^chunk], 16 KB
    __shared__ float  pm1[NW][TOK], pm2[NW][TOK], pz[NW][TOK];
    __shared__ int    pi1[NW][TOK], pi2[NW][TOK];    // +5 KB partials

    const int tid   = threadIdx.x;
    const long tbase = (long)blockIdx.x * TOK;

    // ---- stage x: 4 coalesced float4 loads/thread, XOR-swizzled ds_write ----
    {
        const float4* __restrict__ g4 = reinterpret_cast<const float4*>(x) + tbase * CH;
        #pragma unroll
        for (int j = 0; j < 4; ++j) {
            const int G  = tid + j * 256;            // 0..1023, coalesced
            const int c  = G & 15;                   // chunk
            const int tk = G >> 4;                   // token in block
            const int Gc = (tbase + tk < ntok) ? G : (G & 15);  // clamp tail reads
            xs[c * TOK + (tk ^ c)] = g4[Gc];
        }
    }
    __syncthreads();

    // ---- compute: wave wid owns experts [wid*16, wid*16+16) ----
    const int lane = tid & 63;                       // token in block
    const int wid  = __builtin_amdgcn_readfirstlane(tid >> 6);
    const float4* __restrict__ Wg =
        reinterpret_cast<const float4*>(W) + (size_t)wid * 16 * CH;  // SGPR base

    float m1 = -INFINITY, m2 = -INFINITY, Zp = 0.0f;
    int   i1 = 0, i2 = 0;

    #pragma unroll
    for (int p = 0; p < 2; ++p) {                    // two 8-expert passes
        float acc[ET];
        #pragma unroll
        for (int e = 0; e < ET; ++e) acc[e] = 0.0f;

        #pragma unroll
        for (int k = 0; k < CH; ++k) {
            const float4 xk = xs[k * TOK + (lane ^ k)];   // conflict-free b128
            #pragma unroll
            for (int e = 0; e < ET; ++e) {
                // uniform addr, compile-time offset -> s_load (scalar operand)
                const float4 wv = Wg[(p * ET + e) * CH + k];
                float a = acc[e];
                a = fmaf(xk.x, wv.x, a);
                a = fmaf(xk.y, wv.y, a);
                a = fmaf(xk.z, wv.z, a);
                a = fmaf(xk.w, wv.w, a);
                acc[e] = a;
            }
        }
        // fold pass into running Z + exact top-2 (strict '>' + ascending
        // order => lowest index wins ties, matching lax.top_k)
        #pragma unroll
        for (int e = 0; e < ET; ++e) {
            const float v  = acc[e];
            const int   ge = wid * 16 + p * ET + e;
            Zp += __expf(v);                         // logits ~N(0,1): no max-sub
            const bool b1 = v > m1;
            const bool b2 = v > m2;
            i2 = b1 ? i1 : (b2 ? ge : i2);
            m2 = b1 ? m1 : (b2 ? v : m2);
            i1 = b1 ? ge : i1;
            m1 = b1 ? v  : m1;
        }
    }

    // ---- publish per-wave partials (disjoint, ascending expert ranges) ----
    pm1[wid][lane] = m1;  pm2[wid][lane] = m2;  pz[wid][lane] = Zp;
    pi1[wid][lane] = i1;  pi2[wid][lane] = i2;
    __syncthreads();

    // ---- merge + output: thread -> (token = tid>>2, quarter q = tid&3) ----
    {
        const int tk = tid >> 2;
        const int q  = tid & 3;

        float M1 = pm1[0][tk], M2 = pm2[0][tk], Z = pz[0][tk];
        int   I1 = pi1[0][tk], I2 = pi2[0][tk];
        #pragma unroll
        for (int w = 1; w < NW; ++w) {
            const float b1 = pm1[w][tk], b2 = pm2[w][tk];
            const int   j1 = pi1[w][tk], j2 = pi2[w][tk];
            Z += pz[w][tk];
            // b-range indices all higher than current -> strict '>' keeps
            // lowest-index-wins tie semantics exactly.
            const bool rep = b1 > M1;
            const float nm2 = rep ? ((b2 > M1) ? b2 : M1) : ((b1 > M2) ? b1 : M2);
            const int   ni2 = rep ? ((b2 > M1) ? j2 : I1) : ((b1 > M2) ? j1 : I2);
            M1 = rep ? b1 : M1;
            I1 = rep ? j1 : I1;
            M2 = nm2;  I2 = ni2;
        }

        // out[I1] = sigmoid((E1-E2)/Z), out[I2] = 1 - out[I1]
        const float E1  = __expf(M1), E2 = __expf(M2);
        const float d12 = (E1 - E2) / Z;
        const float w1  = 1.0f / (1.0f + __expf(-d12));
        const float w2  = 1.0f - w1;

        if (tbase + tk < ntok) {
            // thread writes its quarter-row: 4 consecutive float4 = one 64B
            // line fully owned by one lane -> clean write-combining (R6: 64MB)
            float4* __restrict__ o4 =
                reinterpret_cast<float4*>(out) + (tbase + tk) * CH + q * 4;
            #pragma unroll
            for (int kk = 0; kk < 4; ++kk) {
                const int j = q * 16 + kk * 4;
                float4 v;
                v.x = (j + 0 == I1) ? w1 : ((j + 0 == I2) ? w2 : 0.0f);
                v.y = (j + 1 == I1) ? w1 : ((j + 1 == I2) ? w2 : 0.0f);
                v.z = (j + 2 == I1) ? w1 : ((j + 2 == I2) ? w2 : 0.0f);
                v.w = (j + 3 == I1) ? w1 : ((j + 3 == I2) ? w2 : 0.0f);
                o4[kk] = v;
            }
        }
    }
}

extern "C" void kernel_launch(void* const* d_in, const int* in_sizes, int n_in,
                              void* d_out, int out_size, void* d_ws, size_t ws_size,
                              hipStream_t stream) {
    const float* x = (const float*)d_in[0];
    const float* W = (const float*)d_in[1];
    float* out = (float*)d_out;
    int ntok = in_sizes[0] / DIM;                    // 262144

    int blocks = (ntok + TOK - 1) / TOK;             // 4096
    moe_router_kernel<<<blocks, 256, 0, stream>>>(x, W, out, ntok);
}

// Round 8
// 47.943 us; speedup vs baseline: 7.4843x; 1.3223x over previous
//
#include <hip/hip_runtime.h>
#include <math.h>

#define NUM_MOE 64
#define DIM 64
#define CH 16            // float4 chunks per row
#define TOK 64           // tokens per block
#define NW 4             // waves per block
#define ET 8             // experts per inner pass (2 passes per wave)

typedef float f32x2 __attribute__((ext_vector_type(2)));
typedef float f32x4 __attribute__((ext_vector_type(4)));

// R7 structure (4-wave cooperative block, scalar-path W, lane=token fold,
// LDS partial merge) with two targeted fixes:
//  1. token-major LDS with per-token XOR chunk swizzle: staging writes are
//     64 CONTIGUOUS permuted slots per wave (canonical, conflict-free by
//     construction); reads are contiguous-permuted (2-way max = free).
//     R7's 1KB-strided scatter writes were the 6.9M-conflict suspect.
//  2. float2 + __builtin_elementwise_fma -> v_pk_fma_f32 (VOP3P, full
//     rate): halves the FMA issue count (1024 -> 512 per wave).
__global__ __launch_bounds__(256)
void moe_router_kernel(const float* __restrict__ x,
                       const float* __restrict__ W,
                       float* __restrict__ out,
                       int ntok) {
    __shared__ f32x4 xs[TOK * CH];                   // [token][chunk^..], 16 KB
    __shared__ float pm1[NW][TOK], pm2[NW][TOK], pz[NW][TOK];
    __shared__ int   pi1[NW][TOK], pi2[NW][TOK];     // +5 KB partials

    const int tid    = threadIdx.x;
    const long tbase = (long)blockIdx.x * TOK;

    // ---- stage x: coalesced float4 loads -> canonical contiguous writes ----
    {
        const f32x4* __restrict__ g4 = reinterpret_cast<const f32x4*>(x) + tbase * CH;
        #pragma unroll
        for (int j = 0; j < 4; ++j) {
            const int G  = tid + j * 256;            // 0..1023, coalesced read
            const int tk = G >> 4;                   // token in block
            const int c  = G & 15;                   // chunk
            const int Gc = (tbase + tk < ntok) ? G : (G & 15);  // tail clamp
            xs[tk * CH + (c ^ (tk & 7))] = g4[Gc];   // contiguous-permuted write
        }
    }
    __syncthreads();

    // ---- compute: wave wid owns experts [wid*16, wid*16+16) ----
    const int lane = tid & 63;                       // token in block
    const int wid  = __builtin_amdgcn_readfirstlane(tid >> 6);
    const f32x4* __restrict__ Wg =
        reinterpret_cast<const f32x4*>(W) + (size_t)wid * 16 * CH;  // SGPR base

    float m1 = -INFINITY, m2 = -INFINITY, Zp = 0.0f;
    int   i1 = 0, i2 = 0;

    #pragma unroll
    for (int p = 0; p < 2; ++p) {                    // two 8-expert passes
        f32x2 acc[ET];
        #pragma unroll
        for (int e = 0; e < ET; ++e) acc[e] = (f32x2){0.0f, 0.0f};

        #pragma unroll
        for (int k = 0; k < CH; ++k) {
            const f32x4 xk = xs[lane * CH + (k ^ (lane & 7))];  // 2-way max
            const f32x2 xa = {xk.x, xk.y};
            const f32x2 xb = {xk.z, xk.w};
            #pragma unroll
            for (int e = 0; e < ET; ++e) {
                // uniform addr, compile-time offset -> s_load (scalar operand)
                const f32x4 wv = Wg[(p * ET + e) * CH + k];
                const f32x2 wa = {wv.x, wv.y};
                const f32x2 wb = {wv.z, wv.w};
                acc[e] = __builtin_elementwise_fma(xa, wa, acc[e]);  // v_pk_fma_f32
                acc[e] = __builtin_elementwise_fma(xb, wb, acc[e]);
            }
        }
        // fold pass into running Z + exact top-2 (strict '>' + ascending
        // order => lowest index wins ties, matching lax.top_k)
        #pragma unroll
        for (int e = 0; e < ET; ++e) {
            const float v  = acc[e].x + acc[e].y;
            const int   ge = wid * 16 + p * ET + e;
            Zp += __expf(v);                         // logits ~N(0,1): no max-sub
            const bool b1 = v > m1;
            const bool b2 = v > m2;
            i2 = b1 ? i1 : (b2 ? ge : i2);
            m2 = b1 ? m1 : (b2 ? v : m2);
            i1 = b1 ? ge : i1;
            m1 = b1 ? v  : m1;
        }
    }

    // ---- publish per-wave partials (disjoint, ascending expert ranges) ----
    pm1[wid][lane] = m1;  pm2[wid][lane] = m2;  pz[wid][lane] = Zp;
    pi1[wid][lane] = i1;  pi2[wid][lane] = i2;
    __syncthreads();

    // ---- merge + output: thread -> (token = tid>>2, quarter q = tid&3) ----
    {
        const int tk = tid >> 2;
        const int q  = tid & 3;

        float M1 = pm1[0][tk], M2 = pm2[0][tk], Z = pz[0][tk];
        int   I1 = pi1[0][tk], I2 = pi2[0][tk];
        #pragma unroll
        for (int w = 1; w < NW; ++w) {
            const float b1 = pm1[w][tk], b2 = pm2[w][tk];
            const int   j1 = pi1[w][tk], j2 = pi2[w][tk];
            Z += pz[w][tk];
            // b-range indices all higher than current -> strict '>' keeps
            // lowest-index-wins tie semantics exactly.
            const bool rep = b1 > M1;
            const float nm2 = rep ? ((b2 > M1) ? b2 : M1) : ((b1 > M2) ? b1 : M2);
            const int   ni2 = rep ? ((b2 > M1) ? j2 : I1) : ((b1 > M2) ? j1 : I2);
            M1 = rep ? b1 : M1;
            I1 = rep ? j1 : I1;
            M2 = nm2;  I2 = ni2;
        }

        // out[I1] = sigmoid((E1-E2)/Z), out[I2] = 1 - out[I1]
        const float E1  = __expf(M1), E2 = __expf(M2);
        const float d12 = (E1 - E2) / Z;
        const float w1  = 1.0f / (1.0f + __expf(-d12));
        const float w2  = 1.0f - w1;

        if (tbase + tk < ntok) {
            // thread writes its quarter-row: one 64B line fully owned by one
            // lane -> clean write-combining (R7 measured exactly 64 MiB)
            float4* __restrict__ o4 =
                reinterpret_cast<float4*>(out) + (tbase + tk) * CH + q * 4;
            #pragma unroll
            for (int kk = 0; kk < 4; ++kk) {
                const int j = q * 16 + kk * 4;
                float4 v;
                v.x = (j + 0 == I1) ? w1 : ((j + 0 == I2) ? w2 : 0.0f);
                v.y = (j + 1 == I1) ? w1 : ((j + 1 == I2) ? w2 : 0.0f);
                v.z = (j + 2 == I1) ? w1 : ((j + 2 == I2) ? w2 : 0.0f);
                v.w = (j + 3 == I1) ? w1 : ((j + 3 == I2) ? w2 : 0.0f);
                o4[kk] = v;
            }
        }
    }
}

extern "C" void kernel_launch(void* const* d_in, const int* in_sizes, int n_in,
                              void* d_out, int out_size, void* d_ws, size_t ws_size,
                              hipStream_t stream) {
    const float* x = (const float*)d_in[0];
    const float* W = (const float*)d_in[1];
    float* out = (float*)d_out;
    int ntok = in_sizes[0] / DIM;                    // 262144

    int blocks = (ntok + TOK - 1) / TOK;             // 4096
    moe_router_kernel<<<blocks, 256, 0, stream>>>(x, W, out, ntok);
}